// Round 2
// baseline (1085.662 us; speedup 1.0000x reference)
//
#include <hip/hip_runtime.h>

// Grid2Mesh: edge MLP (E=262144, K=384) + gather-mean (K=32) + node MLP (K=256)
// + grid MLP (NG=65536, K=128). bf16 MFMA 16x16x32 with SWAPPED operands:
// mfma(Wfrag, xfrag) -> D^T so each lane owns a full output row (vector epilogue,
// 2-shuffle LN). W staged in LDS as contiguous wave-fragments (zero bank conflict).
// Software-pipelined gathers (pair 2 tiles ahead, rows 1 tile ahead).

typedef __bf16 bf16x8 __attribute__((ext_vector_type(8)));
typedef __bf16 bf16x4 __attribute__((ext_vector_type(4)));
typedef float f32x4 __attribute__((ext_vector_type(4)));

#define E_CNT  262144
#define NG_CNT 65536
#define NM_CNT 8192

__device__ __forceinline__ float fast_tanh(float x) {
    float e = __expf(2.0f * x);
    return 1.0f - 2.0f / (1.0f + e);
}

// MODE 0: A = concat(gm[e], rect[src[e]], mesh[dst[e]]) f32 gather, KDIM=384
// MODE 1: A = precomputed bf16 rows (KDIM=256)
// MODE 2: A = contiguous f32 rows (KDIM=128)
template <int KDIM, int MODE, bool STORE_DELTA>
__global__ __launch_bounds__(1024, 4) void mlp_kernel(
    const float* __restrict__ A0, const float* __restrict__ A1,
    const float* __restrict__ A2, const int* __restrict__ pair,
    const unsigned short* __restrict__ Abf, const float* __restrict__ W,
    const float* __restrict__ gvec, const float* __restrict__ bvec,
    const float* __restrict__ resid, float* __restrict__ out,
    unsigned short* __restrict__ delta_out, int M) {
  constexpr int NKK = KDIM / 32;
  constexpr int NCH = NKK * 8 * 64;          // 16B fragments
  __shared__ __bf16 wt2[NCH * 8];            // KDIM*128 bf16, no padding needed

  const int tid = threadIdx.x;
  // Stage W as wave-fragment-contiguous: chunk c=(kk*8+n)*64+lane holds
  // W[kk*32+q*8+j][n*16+r] for j=0..7 (the MFMA A-operand fragment).
  for (int c = tid; c < NCH; c += 1024) {
    const int lane6 = c & 63;
    const int rr = lane6 & 15, qq = lane6 >> 4;
    const int kkn = c >> 6;
    const int kk = kkn >> 3, nn = kkn & 7;
    const int k0 = kk * 32 + qq * 8;
    const int col = nn * 16 + rr;
    bf16x8 v;
#pragma unroll
    for (int j = 0; j < 8; ++j) v[j] = (__bf16)W[(k0 + j) * 128 + col];
    *(bf16x8*)(wt2 + c * 8) = v;
  }
  __syncthreads();

  const int lane = tid & 63;
  const int wid = tid >> 6;
  const int r = lane & 15, quad = lane >> 4;
  const int wstride = (gridDim.x * 1024) >> 6;
  const int tiles = M >> 4;
  int t = blockIdx.x * 16 + wid;
  if (t >= tiles) return;

  const __bf16* wl = wt2 + lane * 8;
  __bf16* dp = (__bf16*)delta_out;

  // Epilogue: lane (r,quad) holds y[row16+r][n*16+quad*4+j] in acc[n][j].
  auto epilogue = [&](f32x4* acc, int row16, f32x4* R) {
    float tv[8][4];
    float s1 = 0.f, s2 = 0.f;
#pragma unroll
    for (int n = 0; n < 8; ++n)
#pragma unroll
      for (int j = 0; j < 4; ++j) {
        float v = fast_tanh(acc[n][j]);
        tv[n][j] = v;
        s1 += v;
        s2 += v * v;
      }
    s1 += __shfl_xor(s1, 16, 64);
    s2 += __shfl_xor(s2, 16, 64);
    s1 += __shfl_xor(s1, 32, 64);
    s2 += __shfl_xor(s2, 32, 64);
    const float mu = s1 * (1.0f / 128.0f);
    const float rs = rsqrtf(s2 * (1.0f / 128.0f) - mu * mu + 1e-5f);
    const size_t rowbase = (size_t)(row16 + r) * 128;
#pragma unroll
    for (int n = 0; n < 8; ++n) {
      const f32x4 G = *(const f32x4*)(gvec + n * 16 + quad * 4);
      const f32x4 Bv = *(const f32x4*)(bvec + n * 16 + quad * 4);
      f32x4 o;
      bf16x4 db;
#pragma unroll
      for (int j = 0; j < 4; ++j) {
        const float d = (tv[n][j] - mu) * rs * G[j] + Bv[j];
        o[j] = R[n][j] + d;
        db[j] = (__bf16)d;
      }
      *(f32x4*)(out + rowbase + n * 16 + quad * 4) = o;
      if (STORE_DELTA) *(bf16x4*)(dp + rowbase + n * 16 + quad * 4) = db;
    }
  };

  if (MODE == 1) {
    for (; t < tiles; t += wstride) {
      const int row16 = t << 4;
      const unsigned short* pb = Abf + (size_t)(row16 + r) * KDIM + quad * 8;
      bf16x8 ab[NKK];
#pragma unroll
      for (int kk = 0; kk < NKK; ++kk) ab[kk] = *(const bf16x8*)(pb + kk * 32);
      f32x4 R[8];
#pragma unroll
      for (int n = 0; n < 8; ++n)
        R[n] = *(const f32x4*)(resid + (size_t)(row16 + r) * 128 + n * 16 + quad * 4);
      f32x4 acc[8] = {};
#pragma unroll
      for (int kk = 0; kk < NKK; ++kk)
#pragma unroll
        for (int n = 0; n < 8; ++n)
          acc[n] = __builtin_amdgcn_mfma_f32_16x16x32_bf16(
              *(const bf16x8*)(wl + (kk * 8 + n) * 512), ab[kk], acc[n], 0, 0, 0);
      epilogue(acc, row16, R);
    }
    return;
  }

  // MODE 0 / 2: software-pipelined.
  const float* Pn[3];
  auto mkptr = [&](int tt) {
    if (MODE == 0) {
      const int e = (tt << 4) + r;
      const int2 sd = *(const int2*)(pair + 2 * (size_t)e);
      Pn[0] = A0 + (size_t)e * 128;
      Pn[1] = A1 + (size_t)sd.x * 128;
      Pn[2] = A2 + (size_t)sd.y * 128;
    } else {
      Pn[0] = Pn[1] = Pn[2] = A0 + (size_t)((tt << 4) + r) * 128;
    }
  };
  f32x4 F[NKK][2];
  auto issueF = [&]() {
#pragma unroll
    for (int kk = 0; kk < NKK; ++kk) {
      const float* p = Pn[MODE == 0 ? (kk >> 2) : 0] + (kk & 3) * 32 + quad * 8;
      F[kk][0] = *(const f32x4*)p;
      F[kk][1] = *(const f32x4*)(p + 4);
    }
  };

  mkptr(t);
  issueF();                         // gathers for first tile in flight
  const int t1 = t + wstride;
  if (t1 < tiles) mkptr(t1);        // pair for tile t+1 (prologue stall, once)

  while (t < tiles) {
    const int tn = t + wstride;
    const int tnn = tn + wstride;
    int2 sdf;
    if (MODE == 0 && tnn < tiles)   // pair for t+2, issued earliest
      sdf = *(const int2*)(pair + 2 * (size_t)((tnn << 4) + r));
    // convert current tile (waits on F loads issued one iteration ago)
    bf16x8 ab[NKK];
#pragma unroll
    for (int kk = 0; kk < NKK; ++kk)
#pragma unroll
      for (int j = 0; j < 4; ++j) {
        ab[kk][j] = (__bf16)F[kk][0][j];
        ab[kk][4 + j] = (__bf16)F[kk][1][j];
      }
    if (tn < tiles) issueF();       // gathers for next tile fly under MFMA
    const int row16 = t << 4;
    f32x4 R[8];
#pragma unroll
    for (int n = 0; n < 8; ++n)
      R[n] = *(const f32x4*)(resid + (size_t)(row16 + r) * 128 + n * 16 + quad * 4);
    f32x4 acc[8] = {};
#pragma unroll
    for (int kk = 0; kk < NKK; ++kk)
#pragma unroll
      for (int n = 0; n < 8; ++n)
        acc[n] = __builtin_amdgcn_mfma_f32_16x16x32_bf16(
            *(const bf16x8*)(wl + (kk * 8 + n) * 512), ab[kk], acc[n], 0, 0, 0);
    epilogue(acc, row16, R);
    if (tnn < tiles) {
      if (MODE == 0) {
        const int e = (tnn << 4) + r;
        Pn[0] = A0 + (size_t)e * 128;
        Pn[1] = A1 + (size_t)sdf.x * 128;
        Pn[2] = A2 + (size_t)sdf.y * 128;
      } else {
        mkptr(tnn);
      }
    }
    t = tn;
  }
}

// Aggregation: x2[n] = concat(bf16(mesh[n]), bf16(mean_k coef*delta[eid[n][k]]))
template <bool FROM_WS>
__global__ __launch_bounds__(256) void agg_kernel(
    const unsigned short* __restrict__ dws, const float* __restrict__ out0,
    const float* __restrict__ gm, const float* __restrict__ mesh,
    const int* __restrict__ eid, const float* __restrict__ coef,
    unsigned short* __restrict__ x2) {
  __shared__ int eid_s[512];
  __shared__ float cf_s[512];
  const int t = threadIdx.x;
  const int n0 = blockIdx.x * 16;
  for (int i = t; i < 512; i += 256) {
    eid_s[i] = eid[n0 * 32 + i];
    cf_s[i] = coef[n0 * 32 + i];
  }
  __syncthreads();

  const int rl = t >> 4;
  const int d8 = (t & 15) * 8;
  const int row = n0 + rl;

  float acc[8] = {0, 0, 0, 0, 0, 0, 0, 0};
  for (int k = 0; k < 32; ++k) {
    const int e = eid_s[rl * 32 + k];
    const float cf = cf_s[rl * 32 + k];
    if (FROM_WS) {
      bf16x8 v = *(const bf16x8*)((const __bf16*)dws + (size_t)e * 128 + d8);
#pragma unroll
      for (int j = 0; j < 8; ++j) acc[j] += cf * (float)v[j];
    } else {
      const float* po = out0 + (size_t)e * 128 + d8;
      const float* pg = gm + (size_t)e * 128 + d8;
      f32x4 o0 = *(const f32x4*)po, o1 = *(const f32x4*)(po + 4);
      f32x4 g0 = *(const f32x4*)pg, g1 = *(const f32x4*)(pg + 4);
#pragma unroll
      for (int j = 0; j < 4; ++j) {
        acc[j] += cf * (o0[j] - g0[j]);
        acc[4 + j] += cf * (o1[j] - g1[j]);
      }
    }
  }

  const float* pm = mesh + (size_t)row * 128 + d8;
  f32x4 m0 = *(const f32x4*)pm, m1 = *(const f32x4*)(pm + 4);
  bf16x8 mv, av;
#pragma unroll
  for (int j = 0; j < 4; ++j) {
    mv[j] = (__bf16)m0[j];
    mv[4 + j] = (__bf16)m1[j];
  }
#pragma unroll
  for (int j = 0; j < 8; ++j) av[j] = (__bf16)(acc[j] * (1.0f / 32.0f));
  *(bf16x8*)((__bf16*)x2 + (size_t)row * 256 + d8) = mv;
  *(bf16x8*)((__bf16*)x2 + (size_t)row * 256 + 128 + d8) = av;
}

extern "C" void kernel_launch(void* const* d_in, const int* in_sizes, int n_in,
                              void* d_out, int out_size, void* d_ws,
                              size_t ws_size, hipStream_t stream) {
  const float* gm = (const float*)d_in[0];
  const float* rect = (const float*)d_in[1];
  const float* mesh = (const float*)d_in[2];
  const int* pair = (const int*)d_in[3];
  const int* eid = (const int*)d_in[4];
  const float* coef = (const float*)d_in[5];
  const float* W1 = (const float*)d_in[6];
  const float* g1 = (const float*)d_in[7];
  const float* b1 = (const float*)d_in[8];
  const float* W2 = (const float*)d_in[9];
  const float* g2 = (const float*)d_in[10];
  const float* b2 = (const float*)d_in[11];
  const float* W3 = (const float*)d_in[12];
  const float* g3 = (const float*)d_in[13];
  const float* b3 = (const float*)d_in[14];

  float* out0 = (float*)d_out;
  float* out1 = out0 + (size_t)E_CNT * 128;
  float* out2 = out1 + (size_t)NG_CNT * 128;

  unsigned short* dws = (unsigned short*)d_ws;
  const size_t deltaElems = (size_t)E_CNT * 128;
  const size_t x2Elems = (size_t)NM_CNT * 256;
  const bool fast = ws_size >= (deltaElems + x2Elems) * sizeof(unsigned short);

  if (fast) {
    unsigned short* x2 = dws + deltaElems;
    mlp_kernel<384, 0, true><<<256, 1024, 0, stream>>>(
        gm, rect, mesh, pair, nullptr, W1, g1, b1, gm, out0, dws, E_CNT);
    mlp_kernel<128, 2, false><<<256, 1024, 0, stream>>>(
        rect, nullptr, nullptr, nullptr, nullptr, W3, g3, b3, rect, out1,
        nullptr, NG_CNT);
    agg_kernel<true><<<512, 256, 0, stream>>>(dws, nullptr, nullptr, mesh, eid,
                                              coef, x2);
    mlp_kernel<256, 1, false><<<32, 1024, 0, stream>>>(
        nullptr, nullptr, nullptr, nullptr, x2, W2, g2, b2, mesh, out2, nullptr,
        NM_CNT);
  } else {
    unsigned short* x2 = dws;  // needs only 4.2 MB
    mlp_kernel<384, 0, false><<<256, 1024, 0, stream>>>(
        gm, rect, mesh, pair, nullptr, W1, g1, b1, gm, out0, nullptr, E_CNT);
    mlp_kernel<128, 2, false><<<256, 1024, 0, stream>>>(
        rect, nullptr, nullptr, nullptr, nullptr, W3, g3, b3, rect, out1,
        nullptr, NG_CNT);
    agg_kernel<false><<<512, 256, 0, stream>>>(nullptr, out0, gm, mesh, eid,
                                               coef, x2);
    mlp_kernel<256, 1, false><<<32, 1024, 0, stream>>>(
        nullptr, nullptr, nullptr, nullptr, x2, W2, g2, b2, mesh, out2, nullptr,
        NM_CNT);
  }
}

// Round 3
// 544.548 us; speedup vs baseline: 1.9937x; 1.9937x over previous
//
#include <hip/hip_runtime.h>

// Grid2Mesh, restructured via linearity:
//   edge_pre = gm.W0 + rect[src].W1 + mesh[dst].W2
// P1=rect.W1, P2=mesh.W2 precomputed densely (bf16, stashed in d_out regions
// that are overwritten later in the stream). Edge kernel: K=128 MFMA on
// contiguous gm rows + gathered P1/P2 bf16 rows as accumulator init.
// All MFMAs use swapped operands mfma(Wfrag, xfrag) -> lane owns an output row
// (vector epilogue, 2-shuffle LN). W staged in LDS wave-fragment-contiguous
// (zero bank conflict). Register budget kept < 128 unified (1024-thr blocks).

typedef __bf16 bf16x8 __attribute__((ext_vector_type(8)));
typedef __bf16 bf16x4 __attribute__((ext_vector_type(4)));
typedef float f32x4 __attribute__((ext_vector_type(4)));

#define E_CNT  262144
#define NG_CNT 65536
#define NM_CNT 8192

__device__ __forceinline__ float fast_tanh(float x) {
  float e = __expf(2.0f * x);
  return 1.0f - 2.0f / (1.0f + e);
}

// Stage W (KDIMx128 f32, row-major) into LDS as wave-fragment-contiguous bf16:
// chunk c=(kk*8+n)*64+lane, lane=(q*16+cx), holds W[kk*32+q*8+j][n*16+cx].
template <int KDIM>
__device__ __forceinline__ void stage_W(const float* __restrict__ W, __bf16* wt) {
  constexpr int NCH = (KDIM / 32) * 8 * 64;
  for (int c = threadIdx.x; c < NCH; c += blockDim.x) {
    const int lane6 = c & 63;
    const int cx = lane6 & 15, qq = lane6 >> 4;
    const int kkn = c >> 6;
    const int kk = kkn >> 3, nn = kkn & 7;
    const int k0 = kk * 32 + qq * 8;
    const int col = nn * 16 + cx;
    bf16x8 v;
#pragma unroll
    for (int j = 0; j < 8; ++j) v[j] = (__bf16)W[(k0 + j) * 128 + col];
    *(bf16x8*)(wt + c * 8) = v;
  }
}

// Dense K=128 GEMM, raw bf16 output (no activation): out[M][128] = A[M][128].W
__global__ __launch_bounds__(1024, 4) void lin_kernel(
    const float* __restrict__ A, const float* __restrict__ W,
    __bf16* __restrict__ out, int M) {
  __shared__ __bf16 wt[4 * 8 * 64 * 8];  // 32 KB
  stage_W<128>(W, wt);
  __syncthreads();
  const int tid = threadIdx.x, lane = tid & 63, wid = tid >> 6;
  const int r = lane & 15, q = lane >> 4;
  const __bf16* wl = wt + lane * 8;
  const int wstride = (gridDim.x * blockDim.x) >> 6;
  const int tiles = M >> 4;
  for (int t = blockIdx.x * (blockDim.x >> 6) + wid; t < tiles; t += wstride) {
    const int row = (t << 4) + r;
    const float* p = A + (size_t)row * 128 + q * 8;
    f32x4 F[4][2];
#pragma unroll
    for (int kk = 0; kk < 4; ++kk) {
      F[kk][0] = *(const f32x4*)(p + kk * 32);
      F[kk][1] = *(const f32x4*)(p + kk * 32 + 4);
    }
    bf16x8 ab[4];
#pragma unroll
    for (int kk = 0; kk < 4; ++kk)
#pragma unroll
      for (int j = 0; j < 4; ++j) {
        ab[kk][j] = (__bf16)F[kk][0][j];
        ab[kk][4 + j] = (__bf16)F[kk][1][j];
      }
    f32x4 acc[8] = {};
#pragma unroll
    for (int kk = 0; kk < 4; ++kk)
#pragma unroll
      for (int n = 0; n < 8; ++n)
        acc[n] = __builtin_amdgcn_mfma_f32_16x16x32_bf16(
            *(const bf16x8*)(wl + (kk * 8 + n) * 512), ab[kk], acc[n], 0, 0, 0);
    __bf16* po = out + (size_t)row * 128;
#pragma unroll
    for (int n = 0; n < 8; ++n) {
      bf16x4 o;
#pragma unroll
      for (int j = 0; j < 4; ++j) o[j] = (__bf16)acc[n][j];
      *(bf16x4*)(po + n * 16 + q * 4) = o;
    }
  }
}

// Full MLP: y = LN(tanh(A.W + [P1[src]+P2[dst]])) * g + b; out = resid + y.
// MODE 0: A f32 rows (KDIM=128). MODE 1: A bf16 rows (KDIM=256).
template <int KDIM, int MODE, bool ADD_P, bool STORE_DELTA>
__global__ __launch_bounds__(1024, 4) void mlp_kernel(
    const float* __restrict__ Af, const __bf16* __restrict__ Ab,
    const int* __restrict__ pair, const __bf16* __restrict__ P1,
    const __bf16* __restrict__ P2, const float* __restrict__ W,
    const float* __restrict__ gvec, const float* __restrict__ bvec,
    const float* __restrict__ resid, float* __restrict__ out,
    __bf16* __restrict__ delta_out, int M) {
  constexpr int NKK = KDIM / 32;
  __shared__ __bf16 wt[NKK * 8 * 64 * 8];  // 32 KB (K=128) / 64 KB (K=256)
  stage_W<KDIM>(W, wt);
  __syncthreads();
  const int tid = threadIdx.x, lane = tid & 63, wid = tid >> 6;
  const int r = lane & 15, q = lane >> 4;
  const __bf16* wl = wt + lane * 8;
  const int wstride = (gridDim.x * blockDim.x) >> 6;
  const int tiles = M >> 4;
  int t = blockIdx.x * (blockDim.x >> 6) + wid;
  if (t >= tiles) return;

  int2 sd_next = {0, 0};
  bf16x4 pg1[8], pg2[8];
  if (ADD_P) {
    // prologue: gathers for first tile in flight, pair for second tile loaded
    const int2 sd = *(const int2*)(pair + 2 * (size_t)((t << 4) + r));
    const __bf16* p1 = P1 + (size_t)sd.x * 128;
    const __bf16* p2 = P2 + (size_t)sd.y * 128;
#pragma unroll
    for (int n = 0; n < 8; ++n) {
      pg1[n] = *(const bf16x4*)(p1 + n * 16 + q * 4);
      pg2[n] = *(const bf16x4*)(p2 + n * 16 + q * 4);
    }
    if (t + wstride < tiles)
      sd_next = *(const int2*)(pair + 2 * (size_t)(((t + wstride) << 4) + r));
  }

  for (; t < tiles; t += wstride) {
    const int row = (t << 4) + r;
    // A loads (contiguous rows; batched, waited once)
    f32x4 F[4][2];
    bf16x8 ab[NKK];
    if (MODE == 0) {
      const float* p = Af + (size_t)row * 128 + q * 8;
#pragma unroll
      for (int kk = 0; kk < 4; ++kk) {
        F[kk][0] = *(const f32x4*)(p + kk * 32);
        F[kk][1] = *(const f32x4*)(p + kk * 32 + 4);
      }
    } else {
      const __bf16* p = Ab + (size_t)row * KDIM + q * 8;
#pragma unroll
      for (int kk = 0; kk < NKK; ++kk) ab[kk] = *(const bf16x8*)(p + kk * 32);
    }
    // acc init from gathered P rows (loaded last iteration / prologue)
    f32x4 acc[8];
    if (ADD_P) {
#pragma unroll
      for (int n = 0; n < 8; ++n)
#pragma unroll
        for (int j = 0; j < 4; ++j)
          acc[n][j] = (float)pg1[n][j] + (float)pg2[n][j];
      // issue next tile's gathers NOW -> fly under MFMA + epilogue
      if (t + wstride < tiles) {
        const __bf16* p1 = P1 + (size_t)sd_next.x * 128;
        const __bf16* p2 = P2 + (size_t)sd_next.y * 128;
#pragma unroll
        for (int n = 0; n < 8; ++n) {
          pg1[n] = *(const bf16x4*)(p1 + n * 16 + q * 4);
          pg2[n] = *(const bf16x4*)(p2 + n * 16 + q * 4);
        }
        if (t + 2 * wstride < tiles)
          sd_next =
              *(const int2*)(pair + 2 * (size_t)(((t + 2 * wstride) << 4) + r));
      }
    } else {
#pragma unroll
      for (int n = 0; n < 8; ++n) acc[n] = f32x4{0.f, 0.f, 0.f, 0.f};
    }
    if (MODE == 0) {
#pragma unroll
      for (int kk = 0; kk < 4; ++kk)
#pragma unroll
        for (int j = 0; j < 4; ++j) {
          ab[kk][j] = (__bf16)F[kk][0][j];
          ab[kk][4 + j] = (__bf16)F[kk][1][j];
        }
    }
#pragma unroll
    for (int kk = 0; kk < NKK; ++kk)
#pragma unroll
      for (int n = 0; n < 8; ++n)
        acc[n] = __builtin_amdgcn_mfma_f32_16x16x32_bf16(
            *(const bf16x8*)(wl + (kk * 8 + n) * 512), ab[kk], acc[n], 0, 0, 0);

    // epilogue: lane holds y[row][n*16+q*4+j]
    float tv[8][4];
    float s1 = 0.f, s2 = 0.f;
#pragma unroll
    for (int n = 0; n < 8; ++n)
#pragma unroll
      for (int j = 0; j < 4; ++j) {
        float v = fast_tanh(acc[n][j]);
        tv[n][j] = v;
        s1 += v;
        s2 += v * v;
      }
    s1 += __shfl_xor(s1, 16, 64);
    s2 += __shfl_xor(s2, 16, 64);
    s1 += __shfl_xor(s1, 32, 64);
    s2 += __shfl_xor(s2, 32, 64);
    const float mu = s1 * (1.0f / 128.0f);
    const float rs = rsqrtf(s2 * (1.0f / 128.0f) - mu * mu + 1e-5f);
    const float* rp = resid + (size_t)row * 128;
    float* op = out + (size_t)row * 128;
    __bf16* dp = STORE_DELTA ? delta_out + (size_t)row * 128 : nullptr;
#pragma unroll
    for (int n = 0; n < 8; ++n) {
      const f32x4 G = *(const f32x4*)(gvec + n * 16 + q * 4);
      const f32x4 Bv = *(const f32x4*)(bvec + n * 16 + q * 4);
      const f32x4 R = *(const f32x4*)(rp + n * 16 + q * 4);  // L1-hot (MODE0)
      f32x4 o;
      bf16x4 db;
#pragma unroll
      for (int j = 0; j < 4; ++j) {
        const float d = (tv[n][j] - mu) * rs * G[j] + Bv[j];
        o[j] = R[j] + d;
        db[j] = (__bf16)d;
      }
      *(f32x4*)(op + n * 16 + q * 4) = o;
      if (STORE_DELTA) *(bf16x4*)(dp + n * 16 + q * 4) = db;
    }
  }
}

// x2[n] = concat(bf16(mesh[n]), bf16(mean_k coef*delta[eid[n][k]]))
template <bool FROM_WS>
__global__ __launch_bounds__(256) void agg_kernel(
    const __bf16* __restrict__ dws, const float* __restrict__ out0,
    const float* __restrict__ gm, const float* __restrict__ mesh,
    const int* __restrict__ eid, const float* __restrict__ coef,
    __bf16* __restrict__ x2) {
  __shared__ int eid_s[512];
  __shared__ float cf_s[512];
  const int t = threadIdx.x;
  const int n0 = blockIdx.x * 16;
  for (int i = t; i < 512; i += 256) {
    eid_s[i] = eid[n0 * 32 + i];
    cf_s[i] = coef[n0 * 32 + i];
  }
  __syncthreads();
  const int rl = t >> 4;
  const int d8 = (t & 15) * 8;
  const int row = n0 + rl;
  float acc[8] = {0, 0, 0, 0, 0, 0, 0, 0};
  for (int k = 0; k < 32; ++k) {
    const int e = eid_s[rl * 32 + k];
    const float cf = cf_s[rl * 32 + k];
    if (FROM_WS) {
      bf16x8 v = *(const bf16x8*)(dws + (size_t)e * 128 + d8);
#pragma unroll
      for (int j = 0; j < 8; ++j) acc[j] += cf * (float)v[j];
    } else {
      const float* po = out0 + (size_t)e * 128 + d8;
      const float* pg = gm + (size_t)e * 128 + d8;
      f32x4 o0 = *(const f32x4*)po, o1 = *(const f32x4*)(po + 4);
      f32x4 g0 = *(const f32x4*)pg, g1 = *(const f32x4*)(pg + 4);
#pragma unroll
      for (int j = 0; j < 4; ++j) {
        acc[j] += cf * (o0[j] - g0[j]);
        acc[4 + j] += cf * (o1[j] - g1[j]);
      }
    }
  }
  const float* pm = mesh + (size_t)row * 128 + d8;
  f32x4 m0 = *(const f32x4*)pm, m1 = *(const f32x4*)(pm + 4);
  bf16x8 mv, av;
#pragma unroll
  for (int j = 0; j < 4; ++j) {
    mv[j] = (__bf16)m0[j];
    mv[4 + j] = (__bf16)m1[j];
  }
#pragma unroll
  for (int j = 0; j < 8; ++j) av[j] = (__bf16)(acc[j] * (1.0f / 32.0f));
  *(bf16x8*)(x2 + (size_t)row * 256 + d8) = mv;
  *(bf16x8*)(x2 + (size_t)row * 256 + 128 + d8) = av;
}

extern "C" void kernel_launch(void* const* d_in, const int* in_sizes, int n_in,
                              void* d_out, int out_size, void* d_ws,
                              size_t ws_size, hipStream_t stream) {
  const float* gm = (const float*)d_in[0];
  const float* rect = (const float*)d_in[1];
  const float* mesh = (const float*)d_in[2];
  const int* pair = (const int*)d_in[3];
  const int* eid = (const int*)d_in[4];
  const float* coef = (const float*)d_in[5];
  const float* W1 = (const float*)d_in[6];
  const float* g1 = (const float*)d_in[7];
  const float* b1 = (const float*)d_in[8];
  const float* W2 = (const float*)d_in[9];
  const float* g2 = (const float*)d_in[10];
  const float* b2 = (const float*)d_in[11];
  const float* W3 = (const float*)d_in[12];
  const float* g3 = (const float*)d_in[13];
  const float* b3 = (const float*)d_in[14];

  float* out0 = (float*)d_out;
  float* out1 = out0 + (size_t)E_CNT * 128;
  float* out2 = out1 + (size_t)NG_CNT * 128;

  // P1/P2 live in the out1/out2 regions, which are overwritten strictly later
  // in the stream (graph replays the whole sequence each time -> deterministic).
  __bf16* P1 = (__bf16*)out1;
  __bf16* P2 = (__bf16*)out2;

  __bf16* dws = (__bf16*)d_ws;
  const size_t deltaElems = (size_t)E_CNT * 128;
  const size_t x2Elems = (size_t)NM_CNT * 256;
  const bool fast = ws_size >= (deltaElems + x2Elems) * sizeof(__bf16);

  // P1 = rect.W1[128:256], P2 = mesh.W1[256:384]
  lin_kernel<<<256, 1024, 0, stream>>>(rect, W1 + 128 * 128, P1, NG_CNT);
  lin_kernel<<<32, 1024, 0, stream>>>(mesh, W1 + 256 * 128, P2, NM_CNT);

  if (fast) {
    __bf16* x2 = dws + deltaElems;
    mlp_kernel<128, 0, true, true><<<256, 1024, 0, stream>>>(
        gm, nullptr, pair, P1, P2, W1, g1, b1, gm, out0, dws, E_CNT);
    agg_kernel<true><<<512, 256, 0, stream>>>(dws, nullptr, nullptr, mesh, eid,
                                              coef, x2);
    mlp_kernel<128, 0, false, false><<<256, 1024, 0, stream>>>(
        rect, nullptr, nullptr, nullptr, nullptr, W3, g3, b3, rect, out1,
        nullptr, NG_CNT);
    mlp_kernel<256, 1, false, false><<<32, 1024, 0, stream>>>(
        nullptr, x2, nullptr, nullptr, nullptr, W2, g2, b2, mesh, out2, nullptr,
        NM_CNT);
  } else {
    __bf16* x2 = dws;  // only 4.2 MB needed
    mlp_kernel<128, 0, true, false><<<256, 1024, 0, stream>>>(
        gm, nullptr, pair, P1, P2, W1, g1, b1, gm, out0, nullptr, E_CNT);
    agg_kernel<false><<<512, 256, 0, stream>>>(nullptr, out0, gm, mesh, eid,
                                               coef, x2);
    mlp_kernel<128, 0, false, false><<<256, 1024, 0, stream>>>(
        rect, nullptr, nullptr, nullptr, nullptr, W3, g3, b3, rect, out1,
        nullptr, NG_CNT);
    mlp_kernel<256, 1, false, false><<<32, 1024, 0, stream>>>(
        nullptr, x2, nullptr, nullptr, nullptr, W2, g2, b2, mesh, out2, nullptr,
        NM_CNT);
  }
}

// Round 4
// 208.550 us; speedup vs baseline: 5.2058x; 2.6111x over previous
//
#include <hip/hip_runtime.h>

// Grid2Mesh via linearity: edge_pre = gm.W1a + P1[src] + P2[dst],
// P1 = rect.W1b (fused into rect-MLP kernel), P2 = mesh.W1c.
// All matmuls: bf16 MFMA 16x16x32, swapped operands -> lane owns an output row.
// W staged in LDS wave-fragment-contiguous (zero bank conflict).
// 256-thread blocks + amdgpu_waves_per_eu(3,4): no spills (R3's 290MB x2
// scratch traffic), 1 tile/wave exact grids for max outstanding-load depth.

typedef __bf16 bf16x8 __attribute__((ext_vector_type(8)));
typedef __bf16 bf16x4 __attribute__((ext_vector_type(4)));
typedef float f32x4 __attribute__((ext_vector_type(4)));

#define E_CNT 262144
#define NG_CNT 65536
#define NM_CNT 8192

__device__ __forceinline__ float fast_tanh(float x) {
  float e = __expf(2.f * x);
  return 1.f - 2.f / (1.f + e);
}

// Stage W (KDIMx128 f32 row-major) into LDS wave-fragment bf16:
// chunk c=(kk*8+n)*64+lane, lane=(q*16+cx): holds W[kk*32+q*8+j][n*16+cx].
template <int KDIM>
__device__ __forceinline__ void stage_W(const float* __restrict__ W, __bf16* wt) {
  constexpr int NCH = (KDIM / 32) * 8 * 64;
  for (int c = threadIdx.x; c < NCH; c += blockDim.x) {
    const int lane6 = c & 63, cx = lane6 & 15, qq = lane6 >> 4;
    const int kkn = c >> 6, kk = kkn >> 3, nn = kkn & 7;
    const int k0 = kk * 32 + qq * 8, col = nn * 16 + cx;
    bf16x8 v;
#pragma unroll
    for (int j = 0; j < 8; ++j) v[j] = (__bf16)W[(k0 + j) * 128 + col];
    *(bf16x8*)(wt + c * 8) = v;
  }
}

// tanh + LN + residual epilogue; acc[n][j] = pre[row][n*16+q*4+j]; acc reused.
template <bool STORE_D>
__device__ __forceinline__ void mlp_epilogue(f32x4* acc, const f32x4* R,
                                             const float* gvec,
                                             const float* bvec, int q,
                                             float* op, __bf16* dp) {
  float s1 = 0.f, s2 = 0.f;
#pragma unroll
  for (int n = 0; n < 8; ++n)
#pragma unroll
    for (int j = 0; j < 4; ++j) {
      float v = fast_tanh(acc[n][j]);
      acc[n][j] = v;
      s1 += v;
      s2 += v * v;
    }
  s1 += __shfl_xor(s1, 16, 64);
  s2 += __shfl_xor(s2, 16, 64);
  s1 += __shfl_xor(s1, 32, 64);
  s2 += __shfl_xor(s2, 32, 64);
  const float mu = s1 * (1.f / 128.f);
  const float rs = rsqrtf(s2 * (1.f / 128.f) - mu * mu + 1e-5f);
#pragma unroll
  for (int n = 0; n < 8; ++n) {
    const f32x4 G = *(const f32x4*)(gvec + n * 16 + q * 4);
    const f32x4 Bv = *(const f32x4*)(bvec + n * 16 + q * 4);
    f32x4 o;
    bf16x4 db;
#pragma unroll
    for (int j = 0; j < 4; ++j) {
      const float d = (acc[n][j] - mu) * rs * G[j] + Bv[j];
      o[j] = R[n][j] + d;
      db[j] = (__bf16)d;
    }
    *(f32x4*)(op + n * 16 + q * 4) = o;
    if (STORE_D) *(bf16x4*)(dp + n * 16 + q * 4) = db;
  }
}

// Edge kernel: out0 = gm + LN(tanh(gm.W1a + P1[src] + P2[dst]))*g+b, 1 tile/wave.
template <bool STORE_D>
__global__ __launch_bounds__(256) __attribute__((amdgpu_waves_per_eu(3, 4)))
void edge_kernel(const float* __restrict__ gm, const int* __restrict__ pair,
                 const __bf16* __restrict__ P1, const __bf16* __restrict__ P2,
                 const float* __restrict__ W, const float* __restrict__ gvec,
                 const float* __restrict__ bvec, float* __restrict__ out,
                 __bf16* __restrict__ delta_out, int M) {
  __shared__ __bf16 wt[2048 * 8];  // 32 KB
  stage_W<128>(W, wt);
  __syncthreads();
  const int tid = threadIdx.x, lane = tid & 63, wid = tid >> 6;
  const int r = lane & 15, q = lane >> 4;
  const __bf16* wl = wt + lane * 8;
  const int t = blockIdx.x * 4 + wid;
  if (t >= (M >> 4)) return;
  const int row = (t << 4) + r;
  const float* pa = gm + (size_t)row * 128;

  // independent loads first: A fragments + residual row + pair
  f32x4 F[4][2];
#pragma unroll
  for (int kk = 0; kk < 4; ++kk) {
    F[kk][0] = *(const f32x4*)(pa + kk * 32 + q * 8);
    F[kk][1] = *(const f32x4*)(pa + kk * 32 + q * 8 + 4);
  }
  f32x4 R[8];
#pragma unroll
  for (int n = 0; n < 8; ++n) R[n] = *(const f32x4*)(pa + n * 16 + q * 4);
  const int2 sd = *(const int2*)(pair + 2 * (size_t)row);

  // gathered P rows (single dependent hop)
  bf16x4 pg1[8], pg2[8];
  const __bf16* p1 = P1 + (size_t)sd.x * 128 + q * 4;
  const __bf16* p2 = P2 + (size_t)sd.y * 128 + q * 4;
#pragma unroll
  for (int n = 0; n < 8; ++n) {
    pg1[n] = *(const bf16x4*)(p1 + n * 16);
    pg2[n] = *(const bf16x4*)(p2 + n * 16);
  }

  bf16x8 ab[4];
#pragma unroll
  for (int kk = 0; kk < 4; ++kk)
#pragma unroll
    for (int j = 0; j < 4; ++j) {
      ab[kk][j] = (__bf16)F[kk][0][j];
      ab[kk][4 + j] = (__bf16)F[kk][1][j];
    }
  f32x4 acc[8];
#pragma unroll
  for (int n = 0; n < 8; ++n)
#pragma unroll
    for (int j = 0; j < 4; ++j)
      acc[n][j] = (float)pg1[n][j] + (float)pg2[n][j];
#pragma unroll
  for (int kk = 0; kk < 4; ++kk)
#pragma unroll
    for (int n = 0; n < 8; ++n)
      acc[n] = __builtin_amdgcn_mfma_f32_16x16x32_bf16(
          *(const bf16x8*)(wl + (kk * 8 + n) * 512), ab[kk], acc[n], 0, 0, 0);

  mlp_epilogue<STORE_D>(acc, R, gvec, bvec, q, out + (size_t)row * 128,
                        STORE_D ? delta_out + (size_t)row * 128 : nullptr);
}

// Fused rect kernel: P1 = bf16(rect.W1b) AND out1 = rect + mlp(rect, W3).
__global__ __launch_bounds__(256) __attribute__((amdgpu_waves_per_eu(2, 4)))
void rect_fused_kernel(const float* __restrict__ rect,
                       const float* __restrict__ W1b,
                       const float* __restrict__ W3,
                       const float* __restrict__ gvec,
                       const float* __restrict__ bvec,
                       float* __restrict__ out1, __bf16* __restrict__ P1,
                       int M) {
  __shared__ __bf16 wt[4096 * 8];  // 64 KB: [0]=W1b frags, [16384]=W3 frags
  stage_W<128>(W1b, wt);
  stage_W<128>(W3, wt + 16384);
  __syncthreads();
  const int tid = threadIdx.x, lane = tid & 63, wid = tid >> 6;
  const int r = lane & 15, q = lane >> 4;
  const __bf16* wl = wt + lane * 8;
  const int t = blockIdx.x * 4 + wid;
  if (t >= (M >> 4)) return;
  const int row = (t << 4) + r;
  const float* pa = rect + (size_t)row * 128;

  f32x4 F[4][2];
#pragma unroll
  for (int kk = 0; kk < 4; ++kk) {
    F[kk][0] = *(const f32x4*)(pa + kk * 32 + q * 8);
    F[kk][1] = *(const f32x4*)(pa + kk * 32 + q * 8 + 4);
  }
  f32x4 R[8];
#pragma unroll
  for (int n = 0; n < 8; ++n) R[n] = *(const f32x4*)(pa + n * 16 + q * 4);

  bf16x8 ab[4];
#pragma unroll
  for (int kk = 0; kk < 4; ++kk)
#pragma unroll
    for (int j = 0; j < 4; ++j) {
      ab[kk][j] = (__bf16)F[kk][0][j];
      ab[kk][4 + j] = (__bf16)F[kk][1][j];
    }
  f32x4 acc[8] = {};
#pragma unroll
  for (int kk = 0; kk < 4; ++kk)
#pragma unroll
    for (int n = 0; n < 8; ++n)
      acc[n] = __builtin_amdgcn_mfma_f32_16x16x32_bf16(
          *(const bf16x8*)(wl + (kk * 8 + n) * 512), ab[kk], acc[n], 0, 0, 0);
  __bf16* pp = P1 + (size_t)row * 128;
#pragma unroll
  for (int n = 0; n < 8; ++n) {
    bf16x4 o;
#pragma unroll
    for (int j = 0; j < 4; ++j) o[j] = (__bf16)acc[n][j];
    *(bf16x4*)(pp + n * 16 + q * 4) = o;
  }
  f32x4 acc2[8] = {};
#pragma unroll
  for (int kk = 0; kk < 4; ++kk)
#pragma unroll
    for (int n = 0; n < 8; ++n)
      acc2[n] = __builtin_amdgcn_mfma_f32_16x16x32_bf16(
          *(const bf16x8*)(wl + 16384 + (kk * 8 + n) * 512), ab[kk], acc2[n], 0,
          0, 0);
  mlp_epilogue<false>(acc2, R, gvec, bvec, q, out1 + (size_t)row * 128, nullptr);
}

// Plain K=128 MLP (fallback rect path): out = A + mlp(A, W).
__global__ __launch_bounds__(256) __attribute__((amdgpu_waves_per_eu(3, 4)))
void mlp128_kernel(const float* __restrict__ A, const float* __restrict__ W,
                   const float* __restrict__ gvec, const float* __restrict__ bvec,
                   float* __restrict__ out, int M) {
  __shared__ __bf16 wt[2048 * 8];
  stage_W<128>(W, wt);
  __syncthreads();
  const int tid = threadIdx.x, lane = tid & 63, wid = tid >> 6;
  const int r = lane & 15, q = lane >> 4;
  const __bf16* wl = wt + lane * 8;
  const int t = blockIdx.x * 4 + wid;
  if (t >= (M >> 4)) return;
  const int row = (t << 4) + r;
  const float* pa = A + (size_t)row * 128;
  f32x4 F[4][2];
#pragma unroll
  for (int kk = 0; kk < 4; ++kk) {
    F[kk][0] = *(const f32x4*)(pa + kk * 32 + q * 8);
    F[kk][1] = *(const f32x4*)(pa + kk * 32 + q * 8 + 4);
  }
  f32x4 R[8];
#pragma unroll
  for (int n = 0; n < 8; ++n) R[n] = *(const f32x4*)(pa + n * 16 + q * 4);
  bf16x8 ab[4];
#pragma unroll
  for (int kk = 0; kk < 4; ++kk)
#pragma unroll
    for (int j = 0; j < 4; ++j) {
      ab[kk][j] = (__bf16)F[kk][0][j];
      ab[kk][4 + j] = (__bf16)F[kk][1][j];
    }
  f32x4 acc[8] = {};
#pragma unroll
  for (int kk = 0; kk < 4; ++kk)
#pragma unroll
    for (int n = 0; n < 8; ++n)
      acc[n] = __builtin_amdgcn_mfma_f32_16x16x32_bf16(
          *(const bf16x8*)(wl + (kk * 8 + n) * 512), ab[kk], acc[n], 0, 0, 0);
  mlp_epilogue<false>(acc, R, gvec, bvec, q, out + (size_t)row * 128, nullptr);
}

// Dense K=128 linear, bf16 out (P1 fallback / P2).
__global__ __launch_bounds__(256) __attribute__((amdgpu_waves_per_eu(3, 4)))
void lin_kernel(const float* __restrict__ A, const float* __restrict__ W,
                __bf16* __restrict__ out, int M) {
  __shared__ __bf16 wt[2048 * 8];
  stage_W<128>(W, wt);
  __syncthreads();
  const int tid = threadIdx.x, lane = tid & 63, wid = tid >> 6;
  const int r = lane & 15, q = lane >> 4;
  const __bf16* wl = wt + lane * 8;
  const int t = blockIdx.x * 4 + wid;
  if (t >= (M >> 4)) return;
  const int row = (t << 4) + r;
  const float* pa = A + (size_t)row * 128;
  f32x4 F[4][2];
#pragma unroll
  for (int kk = 0; kk < 4; ++kk) {
    F[kk][0] = *(const f32x4*)(pa + kk * 32 + q * 8);
    F[kk][1] = *(const f32x4*)(pa + kk * 32 + q * 8 + 4);
  }
  bf16x8 ab[4];
#pragma unroll
  for (int kk = 0; kk < 4; ++kk)
#pragma unroll
    for (int j = 0; j < 4; ++j) {
      ab[kk][j] = (__bf16)F[kk][0][j];
      ab[kk][4 + j] = (__bf16)F[kk][1][j];
    }
  f32x4 acc[8] = {};
#pragma unroll
  for (int kk = 0; kk < 4; ++kk)
#pragma unroll
    for (int n = 0; n < 8; ++n)
      acc[n] = __builtin_amdgcn_mfma_f32_16x16x32_bf16(
          *(const bf16x8*)(wl + (kk * 8 + n) * 512), ab[kk], acc[n], 0, 0, 0);
  __bf16* po = out + (size_t)row * 128;
#pragma unroll
  for (int n = 0; n < 8; ++n) {
    bf16x4 o;
#pragma unroll
    for (int j = 0; j < 4; ++j) o[j] = (__bf16)acc[n][j];
    *(bf16x4*)(po + n * 16 + q * 4) = o;
  }
}

// Node MLP: K=256, A = x2 bf16 rows, resid = mesh.
__global__ __launch_bounds__(256) __attribute__((amdgpu_waves_per_eu(2, 4)))
void node_kernel(const __bf16* __restrict__ Ab, const float* __restrict__ W,
                 const float* __restrict__ gvec, const float* __restrict__ bvec,
                 const float* __restrict__ resid, float* __restrict__ out,
                 int M) {
  __shared__ __bf16 wt[4096 * 8];  // 64 KB
  stage_W<256>(W, wt);
  __syncthreads();
  const int tid = threadIdx.x, lane = tid & 63, wid = tid >> 6;
  const int r = lane & 15, q = lane >> 4;
  const __bf16* wl = wt + lane * 8;
  const int t = blockIdx.x * 4 + wid;
  if (t >= (M >> 4)) return;
  const int row = (t << 4) + r;
  const __bf16* pb = Ab + (size_t)row * 256 + q * 8;
  bf16x8 ab[8];
#pragma unroll
  for (int kk = 0; kk < 8; ++kk) ab[kk] = *(const bf16x8*)(pb + kk * 32);
  f32x4 R[8];
#pragma unroll
  for (int n = 0; n < 8; ++n)
    R[n] = *(const f32x4*)(resid + (size_t)row * 128 + n * 16 + q * 4);
  f32x4 acc[8] = {};
#pragma unroll
  for (int kk = 0; kk < 8; ++kk)
#pragma unroll
    for (int n = 0; n < 8; ++n)
      acc[n] = __builtin_amdgcn_mfma_f32_16x16x32_bf16(
          *(const bf16x8*)(wl + (kk * 8 + n) * 512), ab[kk], acc[n], 0, 0, 0);
  mlp_epilogue<false>(acc, R, gvec, bvec, q, out + (size_t)row * 128, nullptr);
}

// Aggregation: x2[n] = concat(bf16(mesh[n]), bf16(mean_k coef*delta[eid[n][k]]))
template <bool FROM_WS>
__global__ __launch_bounds__(256) void agg_kernel(
    const __bf16* __restrict__ dws, const float* __restrict__ out0,
    const float* __restrict__ gm, const float* __restrict__ mesh,
    const int* __restrict__ eid, const float* __restrict__ coef,
    __bf16* __restrict__ x2) {
  __shared__ int eid_s[512];
  __shared__ float cf_s[512];
  const int t = threadIdx.x;
  const int n0 = blockIdx.x * 16;
  for (int i = t; i < 512; i += 256) {
    eid_s[i] = eid[n0 * 32 + i];
    cf_s[i] = coef[n0 * 32 + i];
  }
  __syncthreads();
  const int rl = t >> 4;
  const int d8 = (t & 15) * 8;
  const int row = n0 + rl;
  float acc[8] = {0, 0, 0, 0, 0, 0, 0, 0};
  for (int k = 0; k < 32; ++k) {
    const int e = eid_s[rl * 32 + k];
    const float cf = cf_s[rl * 32 + k];
    if (FROM_WS) {
      bf16x8 v = *(const bf16x8*)(dws + (size_t)e * 128 + d8);
#pragma unroll
      for (int j = 0; j < 8; ++j) acc[j] += cf * (float)v[j];
    } else {
      const float* po = out0 + (size_t)e * 128 + d8;
      const float* pg = gm + (size_t)e * 128 + d8;
      f32x4 o0 = *(const f32x4*)po, o1 = *(const f32x4*)(po + 4);
      f32x4 g0 = *(const f32x4*)pg, g1 = *(const f32x4*)(pg + 4);
#pragma unroll
      for (int j = 0; j < 4; ++j) {
        acc[j] += cf * (o0[j] - g0[j]);
        acc[4 + j] += cf * (o1[j] - g1[j]);
      }
    }
  }
  const float* pm = mesh + (size_t)row * 128 + d8;
  f32x4 m0 = *(const f32x4*)pm, m1 = *(const f32x4*)(pm + 4);
  bf16x8 mv, av;
#pragma unroll
  for (int j = 0; j < 4; ++j) {
    mv[j] = (__bf16)m0[j];
    mv[4 + j] = (__bf16)m1[j];
  }
#pragma unroll
  for (int j = 0; j < 8; ++j) av[j] = (__bf16)(acc[j] * (1.0f / 32.0f));
  *(bf16x8*)(x2 + (size_t)row * 256 + d8) = mv;
  *(bf16x8*)(x2 + (size_t)row * 256 + 128 + d8) = av;
}

extern "C" void kernel_launch(void* const* d_in, const int* in_sizes, int n_in,
                              void* d_out, int out_size, void* d_ws,
                              size_t ws_size, hipStream_t stream) {
  const float* gm = (const float*)d_in[0];
  const float* rect = (const float*)d_in[1];
  const float* mesh = (const float*)d_in[2];
  const int* pair = (const int*)d_in[3];
  const int* eid = (const int*)d_in[4];
  const float* coef = (const float*)d_in[5];
  const float* W1 = (const float*)d_in[6];
  const float* g1 = (const float*)d_in[7];
  const float* b1 = (const float*)d_in[8];
  const float* W2 = (const float*)d_in[9];
  const float* g2 = (const float*)d_in[10];
  const float* b2 = (const float*)d_in[11];
  const float* W3 = (const float*)d_in[12];
  const float* g3 = (const float*)d_in[13];
  const float* b3 = (const float*)d_in[14];

  float* out0 = (float*)d_out;
  float* out1 = out0 + (size_t)E_CNT * 128;
  float* out2 = out1 + (size_t)NG_CNT * 128;

  const size_t deltaE = (size_t)E_CNT * 128;    // bf16 elems
  const size_t x2E = (size_t)NM_CNT * 256;
  const size_t p1E = (size_t)NG_CNT * 128;
  const bool fastD = ws_size >= (deltaE + x2E) * 2;
  const bool fastP = ws_size >= (deltaE + x2E + p1E) * 2;

  __bf16* delta = (__bf16*)d_ws;
  __bf16* x2 = fastD ? delta + deltaE : (__bf16*)d_ws;
  __bf16* P1ws = delta + deltaE + x2E;
  __bf16* P2 = (__bf16*)out2;  // overwritten by node_kernel at the end

  const __bf16* P1;
  if (fastP) {
    rect_fused_kernel<<<1024, 256, 0, stream>>>(rect, W1 + 128 * 128, W3, g3,
                                                b3, out1, P1ws, NG_CNT);
    P1 = P1ws;
  } else {
    lin_kernel<<<1024, 256, 0, stream>>>(rect, W1 + 128 * 128, (__bf16*)out1,
                                         NG_CNT);
    P1 = (const __bf16*)out1;
  }
  lin_kernel<<<128, 256, 0, stream>>>(mesh, W1 + 256 * 128, P2, NM_CNT);

  if (fastD) {
    edge_kernel<true><<<4096, 256, 0, stream>>>(gm, pair, P1, P2, W1, g1, b1,
                                                out0, delta, E_CNT);
    agg_kernel<true><<<512, 256, 0, stream>>>(delta, nullptr, nullptr, mesh,
                                              eid, coef, x2);
  } else {
    edge_kernel<false><<<4096, 256, 0, stream>>>(gm, pair, P1, P2, W1, g1, b1,
                                                 out0, nullptr, E_CNT);
    agg_kernel<false><<<512, 256, 0, stream>>>(nullptr, out0, gm, mesh, eid,
                                               coef, x2);
  }
  if (!fastP) {  // rect MLP overwrites out1 only after edge consumed P1
    mlp128_kernel<<<1024, 256, 0, stream>>>(rect, W3, g3, b3, out1, NG_CNT);
  }
  node_kernel<<<128, 256, 0, stream>>>(x2, W2, g2, b2, mesh, out2, NM_CNT);
}